// Round 1
// baseline (2091.349 us; speedup 1.0000x reference)
//
#include <hip/hip_runtime.h>
#include <stdint.h>

typedef unsigned long long u64;
typedef unsigned int u32;
typedef unsigned char u8;

#define Bn 4
#define Nv 8192
#define Fd 64
#define Ed 65536
#define Kv 4096
#define TGTK 4096   // N - K kills allowed
#define NW 256      // alive bitmap words per batch (8192 bits)
#define SC 8192     // bitonic LDS chunk

// ---------------- workspace layout (bytes) ----------------
#define WS_FLAGS   ((size_t)0)                         // 1 u32 presence bits
#define WS_ACCCNT  ((size_t)256)                       // Bn u32
#define WS_OUTBITS ((size_t)512)                       // Bn*Kv*128 u32 = 8 MB
#define OUTBITS_BYTES ((size_t)Bn*Kv*128*4)
#define WS_ZERO_BYTES (WS_OUTBITS + OUTBITS_BYTES)     // memset range
#define WS_KEYS    (WS_ZERO_BYTES)                     // Bn*Ed u64 (8389120: 8-aligned)
#define WS_SQ      (WS_KEYS + (size_t)Bn*Ed*8)         // Bn*Nv f32
#define WS_BND     (WS_SQ + (size_t)Bn*Nv*4)           // Bn*Nv u8
#define WS_OK      (WS_BND + (size_t)Bn*Nv)            // Bn*Ed u8
#define WS_MAP     (WS_OK + (size_t)Bn*Ed)             // Bn*Nv i32
#define WS_POS     (WS_MAP + (size_t)Bn*Nv*4)          // Bn*Nv i32
#define WS_PM      (WS_POS + (size_t)Bn*Nv*4)          // Bn*Nv i32
#define WS_ALIVEW  (WS_PM + (size_t)Bn*Nv*4)           // Bn*NW u32
#define WS_ALIST   (WS_ALIVEW + (size_t)Bn*NW*4)       // Bn*Kv i32
#define WS_ACC     (WS_ALIST + (size_t)Bn*Kv*4)        // Bn*TGTK*2 i32

// ---------------- adj format detection ----------------
// bool-as-byte: nonzero bytes at all offsets%4.  int32 1: only offset%4==0.
// float32 1.0f (00 00 80 3F): offsets 2,3 only.
__global__ void k_detect(const u8* adj, u32* flags) {
    int tid = blockIdx.x * blockDim.x + threadIdx.x;
    const u32* w = (const u32*)adj;
    bool f0 = false, f1 = false, f2 = false, f3 = false;
    for (int i = tid; i < (1 << 19); i += gridDim.x * blockDim.x) { // 2 MB sample
        u32 v = w[i];
        f0 |= (v & 0x000000FFu) != 0;
        f1 |= (v & 0x0000FF00u) != 0;
        f2 |= (v & 0x00FF0000u) != 0;
        f3 |= (v & 0xFF000000u) != 0;
    }
    u32 m = 0;
    if (__ballot(f0)) m |= 1;
    if (__ballot(f1)) m |= 2;
    if (__ballot(f2)) m |= 4;
    if (__ballot(f3)) m |= 8;
    if ((threadIdx.x & 63) == 0 && m) atomicOr(flags, m);
}

// ---------------- per-vertex: numpy-pairwise sqnorm, boundary flag, map init ----------------
__global__ void k_vertex(const float* image, const float* vs, float* sq, u8* bnd, int* map) {
#pragma clang fp contract(off)
    int idx = blockIdx.x * 256 + threadIdx.x; // b*Nv + v
    if (idx >= Bn * Nv) return;
    const float* row = image + (size_t)idx * Fd;
    // numpy pairwise_sum for n=64: 8 accumulators strided 8, tree combine
    float r[8];
#pragma unroll
    for (int j = 0; j < 8; ++j) r[j] = row[j] * row[j];
#pragma unroll
    for (int i = 8; i < 64; i += 8)
#pragma unroll
        for (int j = 0; j < 8; ++j) r[j] += row[i + j] * row[i + j];
    float s = ((r[0] + r[1]) + (r[2] + r[3])) + ((r[4] + r[5]) + (r[6] + r[7]));
    sq[idx] = s;
    float x = vs[(size_t)idx * 2], y = vs[(size_t)idx * 2 + 1];
    const float LO = 0.05f;
    const float HI = (float)(1.0 - 0.05);  // exact f32 of python 1-0.05
    bnd[idx] = ((x < LO) || (x > HI) || (y < LO) || (y > HI)) ? 1 : 0;
    map[idx] = idx & (Nv - 1);  // identity (batch-local vertex id)
}

// ---------------- per-edge: sort key + interior flag ----------------
__global__ void k_edge(const int* edges, const float* sq, const u8* bnd, u64* keys, u8* ok) {
    int idx = blockIdx.x * 256 + threadIdx.x; // b*Ed + e
    if (idx >= Bn * Ed) return;
    int b = idx >> 16, e = idx & (Ed - 1);
    int v0 = edges[(size_t)b * 2 * Ed + e];
    int v1 = edges[(size_t)b * 2 * Ed + Ed + e];
    float c = sq[b * Nv + v0] + sq[b * Nv + v1];
    u32 cb = __float_as_uint(c);              // cost >= 0 -> bits monotone
    keys[idx] = ((u64)cb << 16) | (u32)e;     // stable tie-break by edge id
    ok[idx] = (!bnd[b * Nv + v0] && !bnd[b * Nv + v1]) ? 1 : 0;
}

// ---------------- bitonic sort (per-batch arrays of 65536 u64) ----------------
__device__ __forceinline__ void bitonic_cas(u64* s, int i, int pa, bool asc) {
    u64 a = s[i], c = s[pa];
    if ((a > c) == asc) { s[i] = c; s[pa] = a; }
}

__global__ __launch_bounds__(1024) void k_sortA(u64* keys) { // local sort chunks of SC
    __shared__ u64 s[SC];
    int b = blockIdx.x >> 3, ch = blockIdx.x & 7;
    u64* base = keys + (size_t)b * Ed + (size_t)ch * SC;
    int gb = ch * SC;
    for (int p = 0; p < SC / 1024; ++p) s[p * 1024 + threadIdx.x] = base[p * 1024 + threadIdx.x];
    __syncthreads();
    for (int k = 2; k <= SC; k <<= 1) {
        for (int j = k >> 1; j > 0; j >>= 1) {
            for (int p = 0; p < SC / 2048; ++p) {
                int t = p * 1024 + threadIdx.x;
                int i = ((t & ~(j - 1)) << 1) | (t & (j - 1));
                bool asc = (((gb + i) & k) == 0);
                bitonic_cas(s, i, i | j, asc);
            }
            __syncthreads();
        }
    }
    for (int p = 0; p < SC / 1024; ++p) base[p * 1024 + threadIdx.x] = s[p * 1024 + threadIdx.x];
}

__global__ void k_sortB(u64* keys, int k, int j) { // one global CAS pass
    int idx = blockIdx.x * 256 + threadIdx.x; // Bn*Ed/2
    if (idx >= Bn * Ed / 2) return;
    int b = idx >> 15, t = idx & (Ed / 2 - 1);
    int i = ((t & ~(j - 1)) << 1) | (t & (j - 1));
    int pa = i | j;
    bool asc = ((i & k) == 0);
    u64* base = keys + (size_t)b * Ed;
    u64 a = base[i], c = base[pa];
    if ((a > c) == asc) { base[i] = c; base[pa] = a; }
}

__global__ __launch_bounds__(1024) void k_sortC(u64* keys, int k) { // finish j<=SC/2 in LDS
    __shared__ u64 s[SC];
    int b = blockIdx.x >> 3, ch = blockIdx.x & 7;
    u64* base = keys + (size_t)b * Ed + (size_t)ch * SC;
    int gb = ch * SC;
    for (int p = 0; p < SC / 1024; ++p) s[p * 1024 + threadIdx.x] = base[p * 1024 + threadIdx.x];
    __syncthreads();
    bool asc = ((gb & k) == 0); // k > SC: direction constant per chunk
    for (int j = SC / 2; j > 0; j >>= 1) {
        for (int p = 0; p < SC / 2048; ++p) {
            int t = p * 1024 + threadIdx.x;
            int i = ((t & ~(j - 1)) << 1) | (t & (j - 1));
            bitonic_cas(s, i, i | j, asc);
        }
        __syncthreads();
    }
    for (int p = 0; p < SC / 1024; ++p) base[p * 1024 + threadIdx.x] = s[p * 1024 + threadIdx.x];
}

// ---------------- sequential greedy collapse: 1 wave per batch, 64-edge speculative groups ----------------
__global__ __launch_bounds__(64) void k_greedy(const u64* keys, const int* edges, const u8* ok,
                                               int* map, u32* aliveW, int* accList, u32* accCnt) {
    int b = blockIdx.x;
    int lane = threadIdx.x;
    __shared__ u32 alive[NW];
    __shared__ u32 mlane[Nv]; // per-vertex: min lane registering vertex as its v1 this group
    for (int i = lane; i < NW; i += 64) alive[i] = 0xFFFFFFFFu;
    for (int i = lane; i < Nv; i += 64) mlane[i] = 64u;
    __syncthreads();
    const u64* kb = keys + (size_t)b * Ed;
    const int* e0 = edges + (size_t)b * 2 * Ed;
    const int* e1 = e0 + Ed;
    const u8* okb = ok + (size_t)b * Ed;
    int nk = 0;
    for (int g = 0; g < Ed / 64 && nk < TGTK; ++g) {
        u64 key = kb[g * 64 + lane];
        int id = (int)(key & 0xFFFFu);
        int v0 = e0[id], v1 = e1[id];
        bool okk = okb[id] != 0;
        bool a0 = (alive[v0 >> 5] >> (v0 & 31)) & 1u;
        bool a1 = (alive[v1 >> 5] >> (v1 & 31)) & 1u;
        bool spec = okk && a0 && a1; // exact unless an earlier in-group accept kills my endpoint
        if (spec) atomicMin(&mlane[v1], (u32)lane);
        __syncthreads();
        bool conf = false;
        if (spec) conf = (mlane[v0] < (u32)lane) || (mlane[v1] < (u32)lane);
        u64 specM = __ballot(spec);
        u64 confM = __ballot(conf);
        u64 accM = specM & ~confM; // non-conflicted speculative accepts are exact
        u64 rem = confM;           // resolve conflicted lanes in sequential (edge) order
        while (rem) {
            int l = __ffsll((unsigned long long)rem) - 1;
            rem &= rem - 1;
            int bv0 = __shfl(v0, l);
            int bv1 = __shfl(v1, l);
            bool killer = ((accM >> lane) & 1ull) && (lane < l) && (v1 == bv0 || v1 == bv1);
            if (__ballot(killer) == 0ull) accM |= 1ull << l;
        }
        int cnt = __popcll(accM);
        int remK = TGTK - nk;
        bool acc = (accM >> lane) & 1ull;
        if (cnt > remK) { // kill-count cap: keep first remK accepts; everything later is dead anyway
            int r = __popcll(accM & ((1ull << lane) - 1ull));
            if (acc && r >= remK) acc = false;
            accM = __ballot(acc);
            cnt = remK;
        }
        if (acc) {
            atomicAnd(&alive[v1 >> 5], ~(1u << (v1 & 31)));
            map[(size_t)b * Nv + v1] = v0;
            int r = __popcll(accM & ((1ull << lane) - 1ull));
            int slot = nk + r;
            accList[((size_t)b * TGTK + slot) * 2] = v0;
            accList[((size_t)b * TGTK + slot) * 2 + 1] = v1;
        }
        if (spec) mlane[v1] = 64u; // reset registry
        nk += cnt;
        __syncthreads();
    }
    for (int i = lane; i < NW; i += 64) aliveW[b * NW + i] = alive[i];
    if (lane == 0) accCnt[b] = (u32)nk;
}

// ---------------- alive ranks: pos[v], alive list, pm[v] = pos[m[v]] ----------------
__global__ __launch_bounds__(256) void k_scan(const u32* aliveW, const int* map,
                                              int* pos, int* pm, int* alist) {
    int b = blockIdx.x, tid = threadIdx.x;
    __shared__ u32 cnt[256];
    __shared__ u32 off[256];
    u32 w = aliveW[b * NW + tid];
    cnt[tid] = __popc(w);
    __syncthreads();
    if (tid == 0) { u32 s = 0; for (int i = 0; i < 256; ++i) { off[i] = s; s += cnt[i]; } }
    __syncthreads();
    u32 base = off[tid];
    int* posb = pos + (size_t)b * Nv;
    int* alb = alist + (size_t)b * Kv;
    for (int bit = 0; bit < 32; ++bit) {
        int v = tid * 32 + bit;
        int p = -1;
        if ((w >> bit) & 1u) {
            if (base < Kv) { p = (int)base; alb[base] = v; }
            base++;
        }
        posb[v] = p;
    }
    __syncthreads();
    const int* mapb = map + (size_t)b * Nv;
    int* pmb = pm + (size_t)b * Nv;
    for (int v = tid; v < Nv; v += 256) pmb[v] = posb[mapb[v]];
}

// ---------------- features: copy surviving rows, then scatter-add absorbed rows ----------------
__global__ void k_fcopy(const float* image, const int* alist, float* outF) {
    int idx = blockIdx.x * 256 + threadIdx.x; // Bn*Kv*16
    if (idx >= Bn * Kv * 16) return;
    int b = idx >> 16, r = idx & 65535;
    int x = r >> 4, f4 = r & 15;
    int src = alist[b * Kv + x];
    const float4* s = (const float4*)(image + ((size_t)(b * Nv + src)) * Fd) + f4;
    float4* d = (float4*)(outF + ((size_t)(b * Kv + x)) * Fd) + f4;
    *d = *s;
}

__global__ __launch_bounds__(64) void k_fscat(const float* image, const int* accList,
                                              const u32* accCnt, const int* pos, float* outF) {
    int b = blockIdx.x >> 12, e = blockIdx.x & 4095;
    if (e >= (int)accCnt[b]) return;
    int v0 = accList[((size_t)b * TGTK + e) * 2];
    int v1 = accList[((size_t)b * TGTK + e) * 2 + 1];
    int x = pos[(size_t)b * Nv + v0];
    if (x < 0) return;
    int f = threadIdx.x;
    atomicAdd(outF + ((size_t)(b * Kv + x)) * Fd + f,
              image[((size_t)(b * Nv + v1)) * Fd + f]);
}

// ---------------- adjacency: merge rows/cols into K-bit bitsets ----------------
__global__ __launch_bounds__(256) void k_merge(const u8* adj, const u32* flags,
                                               const int* pm, u32* outbits) {
    int bi = blockIdx.x; // Bn*Nv
    int b = bi >> 13, i = bi & (Nv - 1);
    int t = pm[(size_t)b * Nv + i];
    if (t < 0) return;
    __shared__ u32 bits[Kv / 32]; // 128 words
    int tid = threadIdx.x;
    if (tid < 128) bits[tid] = 0;
    __syncthreads();
    const int* pmb = pm + (size_t)b * Nv;
    u32 fw = flags[0];
    bool bytefmt = (fw & 1) && (fw & 8); // byte-bool; int32 -> p0 only; float32 -> p3 only
    auto put = [&](int col) {
        int c = pmb[col];
        if (c >= 0) atomicOr(&bits[c >> 5], 1u << (c & 31));
    };
    if (bytefmt) {
        const uint4* row = (const uint4*)(adj + ((size_t)b * Nv + i) * Nv);
#pragma unroll
        for (int it = 0; it < 2; ++it) {
            uint4 v = row[it * 256 + tid];
            if (v.x | v.y | v.z | v.w) {
                int cb = (it * 256 + tid) * 16;
                u32 wv[4] = { v.x, v.y, v.z, v.w };
                for (int q = 0; q < 4; ++q) {
                    u32 u = wv[q];
                    if (!u) continue;
#pragma unroll
                    for (int kk = 0; kk < 4; ++kk)
                        if ((u >> (8 * kk)) & 0xFFu) put(cb + q * 4 + kk);
                }
            }
        }
    } else { // 4-byte elements (int32 or float32): nonzero word == true
        const uint4* row = (const uint4*)((const u32*)adj + ((size_t)b * Nv + i) * Nv);
        for (int it = 0; it < 8; ++it) {
            uint4 v = row[it * 256 + tid];
            int cb = (it * 256 + tid) * 4;
            if (v.x) put(cb);
            if (v.y) put(cb + 1);
            if (v.z) put(cb + 2);
            if (v.w) put(cb + 3);
        }
    }
    __syncthreads();
    if (tid < 128) {
        u32 bw = bits[tid];
        if (bw) atomicOr(&outbits[((size_t)b * Kv + t) * 128 + tid], bw);
    }
}

// ---------------- expand bitsets to float adjacency, zero diagonal ----------------
__global__ void k_expand(const u32* outbits, float* out) {
    int idx = blockIdx.x; // Bn*Kv*4
    int tid = threadIdx.x;
    int b = idx >> 14, r = idx & 16383;
    int x = r >> 2, seg = r & 3;
    int c0 = seg * 1024 + tid * 4;
    u32 w = outbits[((size_t)b * Kv + x) * 128 + (c0 >> 5)];
    u32 nib = (w >> (c0 & 31)) & 0xFu;
    float4 f;
    f.x = (nib & 1) ? 1.f : 0.f;
    f.y = (nib & 2) ? 1.f : 0.f;
    f.z = (nib & 4) ? 1.f : 0.f;
    f.w = (nib & 8) ? 1.f : 0.f;
    if (x >= c0 && x < c0 + 4) ((float*)&f)[x - c0] = 0.f;
    *((float4*)(out + ((size_t)(b * Kv + x)) * Kv + c0)) = f;
}

extern "C" void kernel_launch(void* const* d_in, const int* in_sizes, int n_in,
                              void* d_out, int out_size, void* d_ws, size_t ws_size,
                              hipStream_t stream) {
    const u8* adj = (const u8*)d_in[0];
    const float* image = (const float*)d_in[1];
    const float* vs = (const float*)d_in[2];
    const int* edges = (const int*)d_in[3];
    char* ws = (char*)d_ws;
    u32* flags = (u32*)(ws + WS_FLAGS);
    u32* accCnt = (u32*)(ws + WS_ACCCNT);
    u32* outbits = (u32*)(ws + WS_OUTBITS);
    u64* keys = (u64*)(ws + WS_KEYS);
    float* sq = (float*)(ws + WS_SQ);
    u8* bnd = (u8*)(ws + WS_BND);
    u8* ok = (u8*)(ws + WS_OK);
    int* map = (int*)(ws + WS_MAP);
    int* pos = (int*)(ws + WS_POS);
    int* pm = (int*)(ws + WS_PM);
    u32* aliveW = (u32*)(ws + WS_ALIVEW);
    int* alist = (int*)(ws + WS_ALIST);
    int* accList = (int*)(ws + WS_ACC);
    float* outA = (float*)d_out;
    float* outF = outA + (size_t)Bn * Kv * Kv;

    hipMemsetAsync(d_ws, 0, WS_ZERO_BYTES, stream);
    k_detect<<<64, 256, 0, stream>>>(adj, flags);
    k_vertex<<<Bn * Nv / 256, 256, 0, stream>>>(image, vs, sq, bnd, map);
    k_edge<<<Bn * Ed / 256, 256, 0, stream>>>(edges, sq, bnd, keys, ok);
    // bitonic sort: local chunks, then merge stages
    k_sortA<<<Bn * 8, 1024, 0, stream>>>(keys);
    k_sortB<<<Bn * Ed / 2 / 256, 256, 0, stream>>>(keys, 16384, 8192);
    k_sortC<<<Bn * 8, 1024, 0, stream>>>(keys, 16384);
    k_sortB<<<Bn * Ed / 2 / 256, 256, 0, stream>>>(keys, 32768, 16384);
    k_sortB<<<Bn * Ed / 2 / 256, 256, 0, stream>>>(keys, 32768, 8192);
    k_sortC<<<Bn * 8, 1024, 0, stream>>>(keys, 32768);
    k_sortB<<<Bn * Ed / 2 / 256, 256, 0, stream>>>(keys, 65536, 32768);
    k_sortB<<<Bn * Ed / 2 / 256, 256, 0, stream>>>(keys, 65536, 16384);
    k_sortB<<<Bn * Ed / 2 / 256, 256, 0, stream>>>(keys, 65536, 8192);
    k_sortC<<<Bn * 8, 1024, 0, stream>>>(keys, 65536);
    k_greedy<<<Bn, 64, 0, stream>>>(keys, edges, ok, map, aliveW, accList, accCnt);
    k_scan<<<Bn, 256, 0, stream>>>(aliveW, map, pos, pm, alist);
    k_fcopy<<<Bn * Kv * 16 / 256, 256, 0, stream>>>(image, alist, outF);
    k_fscat<<<Bn * TGTK, 64, 0, stream>>>(image, accList, accCnt, pos, outF);
    k_merge<<<Bn * Nv, 256, 0, stream>>>(adj, flags, pm, outbits);
    k_expand<<<Bn * Kv * 4, 256, 0, stream>>>(outbits, outA);
}

// Round 2
// 2013.404 us; speedup vs baseline: 1.0387x; 1.0387x over previous
//
#include <hip/hip_runtime.h>
#include <stdint.h>

typedef unsigned long long u64;
typedef unsigned int u32;
typedef unsigned char u8;

#define Bn 4
#define Nv 8192
#define Fd 64
#define Ed 65536
#define Kv 4096
#define TGTK 4096   // N - K kills allowed
#define NW 256      // alive bitmap words per batch (8192 bits)
#define SC 8192     // bitonic LDS chunk

// ---------------- workspace layout (bytes) ----------------
#define WS_FLAGS   ((size_t)0)                         // 1 u32 presence bits
#define WS_ACCCNT  ((size_t)256)                       // Bn u32
#define WS_OUTBITS ((size_t)512)                       // Bn*Kv*128 u32 = 8 MB
#define OUTBITS_BYTES ((size_t)Bn*Kv*128*4)
#define WS_ZERO_BYTES (WS_OUTBITS + OUTBITS_BYTES)     // memset range
#define WS_KEYS    (WS_ZERO_BYTES)                     // Bn*Ed u64 (8-aligned)
#define WS_SQ      (WS_KEYS + (size_t)Bn*Ed*8)         // Bn*Nv f32
#define WS_BND     (WS_SQ + (size_t)Bn*Nv*4)           // Bn*Nv u8
#define WS_MAP     (WS_BND + (size_t)Bn*Nv)            // Bn*Nv i32
#define WS_POS     (WS_MAP + (size_t)Bn*Nv*4)          // Bn*Nv i32
#define WS_PM      (WS_POS + (size_t)Bn*Nv*4)          // Bn*Nv i32
#define WS_ALIVEW  (WS_PM + (size_t)Bn*Nv*4)           // Bn*NW u32
#define WS_ALIST   (WS_ALIVEW + (size_t)Bn*NW*4)       // Bn*Kv i32
#define WS_ACC     (WS_ALIST + (size_t)Bn*Kv*4)        // Bn*TGTK*2 i32
#define WS_PACK    (WS_ACC + (size_t)Bn*TGTK*2*4)      // Bn*Ed u32
#define WS_SPACK   (WS_PACK + (size_t)Bn*Ed*4)         // Bn*Ed u32

// ---------------- adj format detection ----------------
__global__ void k_detect(const u8* adj, u32* flags) {
    int tid = blockIdx.x * blockDim.x + threadIdx.x;
    const u32* w = (const u32*)adj;
    bool f0 = false, f1 = false, f2 = false, f3 = false;
    for (int i = tid; i < (1 << 19); i += gridDim.x * blockDim.x) { // 2 MB sample
        u32 v = w[i];
        f0 |= (v & 0x000000FFu) != 0;
        f1 |= (v & 0x0000FF00u) != 0;
        f2 |= (v & 0x00FF0000u) != 0;
        f3 |= (v & 0xFF000000u) != 0;
    }
    u32 m = 0;
    if (__ballot(f0)) m |= 1;
    if (__ballot(f1)) m |= 2;
    if (__ballot(f2)) m |= 4;
    if (__ballot(f3)) m |= 8;
    if ((threadIdx.x & 63) == 0 && m) atomicOr(flags, m);
}

// ---------------- per-vertex: numpy-pairwise sqnorm, boundary flag, map init ----------------
__global__ void k_vertex(const float* image, const float* vs, float* sq, u8* bnd, int* map) {
#pragma clang fp contract(off)
    int idx = blockIdx.x * 256 + threadIdx.x; // b*Nv + v
    if (idx >= Bn * Nv) return;
    const float* row = image + (size_t)idx * Fd;
    float r[8];
#pragma unroll
    for (int j = 0; j < 8; ++j) r[j] = row[j] * row[j];
#pragma unroll
    for (int i = 8; i < 64; i += 8)
#pragma unroll
        for (int j = 0; j < 8; ++j) r[j] += row[i + j] * row[i + j];
    float s = ((r[0] + r[1]) + (r[2] + r[3])) + ((r[4] + r[5]) + (r[6] + r[7]));
    sq[idx] = s;
    float x = vs[(size_t)idx * 2], y = vs[(size_t)idx * 2 + 1];
    const float LO = 0.05f;
    const float HI = (float)(1.0 - 0.05);
    bnd[idx] = ((x < LO) || (x > HI) || (y < LO) || (y > HI)) ? 1 : 0;
    map[idx] = idx & (Nv - 1);
}

// ---------------- per-edge: sort key + packed (v0,v1,ok) ----------------
__global__ void k_edge(const int* edges, const float* sq, const u8* bnd, u64* keys, u32* pack) {
    int idx = blockIdx.x * 256 + threadIdx.x; // b*Ed + e
    if (idx >= Bn * Ed) return;
    int b = idx >> 16, e = idx & (Ed - 1);
    int v0 = edges[(size_t)b * 2 * Ed + e];
    int v1 = edges[(size_t)b * 2 * Ed + Ed + e];
    float c = sq[b * Nv + v0] + sq[b * Nv + v1];
    keys[idx] = ((u64)__float_as_uint(c) << 16) | (u32)e; // cost>=0: bits monotone; id tie-break
    u32 okk = (!bnd[b * Nv + v0] && !bnd[b * Nv + v1]) ? 1u : 0u;
    pack[idx] = (u32)v0 | ((u32)v1 << 13) | (okk << 26);
}

// ---------------- bitonic sort (per-batch arrays of 65536 u64) ----------------
__device__ __forceinline__ void bitonic_cas(u64* s, int i, int pa, bool asc) {
    u64 a = s[i], c = s[pa];
    if ((a > c) == asc) { s[i] = c; s[pa] = a; }
}
__device__ __forceinline__ void cex(u64& a, u64& b, bool asc) {
    if ((a > b) == asc) { u64 t = a; a = b; b = t; }
}

// local sort chunks of SC; j<=4 stages in registers (thread owns 8 contiguous elems)
__global__ __launch_bounds__(1024) void k_sortA(u64* keys) {
    __shared__ u64 s[SC];
    int b = blockIdx.x >> 3, ch = blockIdx.x & 7;
    u64* base = keys + (size_t)b * Ed + (size_t)ch * SC;
    int gb = ch * SC;
    int t8 = threadIdx.x * 8;
    u64 r[8];
#pragma unroll
    for (int u = 0; u < 8; ++u) r[u] = base[t8 + u];
    // k=2 (asc = (u&2)==0 since (gb+8t)&2 == 0)
    cex(r[0], r[1], true); cex(r[2], r[3], false); cex(r[4], r[5], true); cex(r[6], r[7], false);
    // k=4
    cex(r[0], r[2], true); cex(r[1], r[3], true); cex(r[4], r[6], false); cex(r[5], r[7], false);
    cex(r[0], r[1], true); cex(r[2], r[3], true); cex(r[4], r[5], false); cex(r[6], r[7], false);
    // k=8 (direction uniform within thread)
    {
        bool a8 = (((gb + t8) & 8) == 0);
        cex(r[0], r[4], a8); cex(r[1], r[5], a8); cex(r[2], r[6], a8); cex(r[3], r[7], a8);
        cex(r[0], r[2], a8); cex(r[1], r[3], a8); cex(r[4], r[6], a8); cex(r[5], r[7], a8);
        cex(r[0], r[1], a8); cex(r[2], r[3], a8); cex(r[4], r[5], a8); cex(r[6], r[7], a8);
    }
#pragma unroll
    for (int u = 0; u < 8; ++u) s[t8 + u] = r[u];
    __syncthreads();
    for (int k = 16; k <= SC; k <<= 1) {
        for (int j = k >> 1; j >= 8; j >>= 1) {
#pragma unroll
            for (int p = 0; p < SC / 2048; ++p) {
                int t = p * 1024 + threadIdx.x;
                int i = ((t & ~(j - 1)) << 1) | (t & (j - 1));
                bool asc = (((gb + i) & k) == 0);
                bitonic_cas(s, i, i | j, asc);
            }
            __syncthreads();
        }
        // j = 4,2,1 in registers; direction uniform over 8 contiguous (k>=16)
        bool asc = (((gb + t8) & k) == 0);
#pragma unroll
        for (int u = 0; u < 8; ++u) r[u] = s[t8 + u];
        cex(r[0], r[4], asc); cex(r[1], r[5], asc); cex(r[2], r[6], asc); cex(r[3], r[7], asc);
        cex(r[0], r[2], asc); cex(r[1], r[3], asc); cex(r[4], r[6], asc); cex(r[5], r[7], asc);
        cex(r[0], r[1], asc); cex(r[2], r[3], asc); cex(r[4], r[5], asc); cex(r[6], r[7], asc);
        if (k == SC) {
#pragma unroll
            for (int u = 0; u < 8; ++u) base[t8 + u] = r[u];
        } else {
#pragma unroll
            for (int u = 0; u < 8; ++u) s[t8 + u] = r[u];
            __syncthreads();
        }
    }
}

__global__ void k_sortB(u64* keys, int k, int j) { // one global CAS pass
    int idx = blockIdx.x * 256 + threadIdx.x; // Bn*Ed/2
    if (idx >= Bn * Ed / 2) return;
    int b = idx >> 15, t = idx & (Ed / 2 - 1);
    int i = ((t & ~(j - 1)) << 1) | (t & (j - 1));
    int pa = i | j;
    bool asc = ((i & k) == 0);
    u64* base = keys + (size_t)b * Ed;
    u64 a = base[i], c = base[pa];
    if ((a > c) == asc) { base[i] = c; base[pa] = a; }
}

// finish j<=SC/2 in LDS (k > SC: direction constant per chunk); j<=4 in registers
__global__ __launch_bounds__(1024) void k_sortC(u64* keys, int k) {
    __shared__ u64 s[SC];
    int b = blockIdx.x >> 3, ch = blockIdx.x & 7;
    u64* base = keys + (size_t)b * Ed + (size_t)ch * SC;
    int gb = ch * SC;
    for (int p = 0; p < SC / 1024; ++p) s[p * 1024 + threadIdx.x] = base[p * 1024 + threadIdx.x];
    __syncthreads();
    bool asc = ((gb & k) == 0);
    for (int j = SC / 2; j >= 8; j >>= 1) {
#pragma unroll
        for (int p = 0; p < SC / 2048; ++p) {
            int t = p * 1024 + threadIdx.x;
            int i = ((t & ~(j - 1)) << 1) | (t & (j - 1));
            bitonic_cas(s, i, i | j, asc);
        }
        __syncthreads();
    }
    int t8 = threadIdx.x * 8;
    u64 r[8];
#pragma unroll
    for (int u = 0; u < 8; ++u) r[u] = s[t8 + u];
    cex(r[0], r[4], asc); cex(r[1], r[5], asc); cex(r[2], r[6], asc); cex(r[3], r[7], asc);
    cex(r[0], r[2], asc); cex(r[1], r[3], asc); cex(r[4], r[6], asc); cex(r[5], r[7], asc);
    cex(r[0], r[1], asc); cex(r[2], r[3], asc); cex(r[4], r[5], asc); cex(r[6], r[7], asc);
#pragma unroll
    for (int u = 0; u < 8; ++u) base[t8 + u] = r[u];
}

// ---------------- permute packs into sorted order (kills gathers in serial loop) ----------------
__global__ void k_gather(const u64* keys, const u32* pack, u32* spack) {
    int idx = blockIdx.x * 256 + threadIdx.x;
    if (idx >= Bn * Ed) return;
    int b = idx >> 16;
    u32 id = (u32)(keys[idx] & 0xFFFFu);
    spack[idx] = pack[(size_t)b * Ed + id];
}

// ---------------- sequential greedy collapse: 1 wave per batch, 64-edge speculative groups ----------------
__global__ __launch_bounds__(64) void k_greedy(const u32* spack, int* map, u32* aliveW,
                                               int* accList, u32* accCnt) {
    int b = blockIdx.x;
    int lane = threadIdx.x;
    __shared__ u32 alive[NW];
    __shared__ u32 mlane[Nv]; // per-vertex: min lane registering vertex as its v1 this group
    for (int i = lane; i < NW; i += 64) alive[i] = 0xFFFFFFFFu;
    for (int i = lane; i < Nv; i += 64) mlane[i] = 64u;
    const u32* sp = spack + (size_t)b * Ed;
    u32 pc = sp[lane]; // prefetch group 0
    __syncthreads();
    int nk = 0;
    const int G = Ed / 64;
    for (int g = 0; g < G; ++g) {
        u32 pn = (g + 1 < G) ? sp[(g + 1) * 64 + lane] : 0u; // prefetch next group (coalesced)
        int v0 = pc & 8191;
        int v1 = (pc >> 13) & 8191;
        bool okk = (pc >> 26) & 1u;
        bool a0 = (alive[v0 >> 5] >> (v0 & 31)) & 1u;
        bool a1 = (alive[v1 >> 5] >> (v1 & 31)) & 1u;
        bool spec = okk && a0 && a1; // exact unless an earlier in-group accept kills my endpoint
        if (spec) atomicMin(&mlane[v1], (u32)lane);
        __syncthreads();
        bool conf = false;
        if (spec) conf = (mlane[v0] < (u32)lane) || (mlane[v1] < (u32)lane);
        u64 specM = __ballot(spec);
        u64 confM = __ballot(conf);
        u64 accM = specM & ~confM; // non-conflicted speculative accepts are exact
        u64 rem = confM;           // resolve conflicted lanes in sequential (edge) order
        while (rem) {
            int l = __ffsll((unsigned long long)rem) - 1;
            rem &= rem - 1;
            int bv0 = __shfl(v0, l);
            int bv1 = __shfl(v1, l);
            bool killer = ((accM >> lane) & 1ull) && (lane < l) && (v1 == bv0 || v1 == bv1);
            if (__ballot(killer) == 0ull) accM |= 1ull << l;
        }
        int cnt = __popcll(accM);
        int remK = TGTK - nk;
        bool acc = (accM >> lane) & 1ull;
        if (cnt > remK) { // kill-count cap: keep first remK accepts
            int rr = __popcll(accM & ((1ull << lane) - 1ull));
            if (acc && rr >= remK) acc = false;
            accM = __ballot(acc);
            cnt = remK;
        }
        if (acc) {
            atomicAnd(&alive[v1 >> 5], ~(1u << (v1 & 31)));
            map[(size_t)b * Nv + v1] = v0;
            int rr = __popcll(accM & ((1ull << lane) - 1ull));
            int slot = nk + rr;
            accList[((size_t)b * TGTK + slot) * 2] = v0;
            accList[((size_t)b * TGTK + slot) * 2 + 1] = v1;
        }
        if (spec) mlane[v1] = 64u; // reset registry
        nk += cnt;
        __syncthreads();
        if (nk >= TGTK) break;
        pc = pn;
    }
    for (int i = lane; i < NW; i += 64) aliveW[b * NW + i] = alive[i];
    if (lane == 0) accCnt[b] = (u32)nk;
}

// ---------------- alive ranks: pos[v], alive list, pm[v] = pos[m[v]] ----------------
__global__ __launch_bounds__(256) void k_scan(const u32* aliveW, const int* map,
                                              int* pos, int* pm, int* alist) {
    int b = blockIdx.x, tid = threadIdx.x;
    __shared__ u32 cnt[256];
    __shared__ u32 off[256];
    u32 w = aliveW[b * NW + tid];
    cnt[tid] = __popc(w);
    __syncthreads();
    if (tid == 0) { u32 s = 0; for (int i = 0; i < 256; ++i) { off[i] = s; s += cnt[i]; } }
    __syncthreads();
    u32 base = off[tid];
    int* posb = pos + (size_t)b * Nv;
    int* alb = alist + (size_t)b * Kv;
    for (int bit = 0; bit < 32; ++bit) {
        int v = tid * 32 + bit;
        int p = -1;
        if ((w >> bit) & 1u) {
            if (base < Kv) { p = (int)base; alb[base] = v; }
            base++;
        }
        posb[v] = p;
    }
    __syncthreads();
    const int* mapb = map + (size_t)b * Nv;
    int* pmb = pm + (size_t)b * Nv;
    for (int v = tid; v < Nv; v += 256) pmb[v] = posb[mapb[v]];
}

// ---------------- features: copy surviving rows, then scatter-add absorbed rows ----------------
__global__ void k_fcopy(const float* image, const int* alist, float* outF) {
    int idx = blockIdx.x * 256 + threadIdx.x; // Bn*Kv*16
    if (idx >= Bn * Kv * 16) return;
    int b = idx >> 16, r = idx & 65535;
    int x = r >> 4, f4 = r & 15;
    int src = alist[b * Kv + x];
    const float4* s = (const float4*)(image + ((size_t)(b * Nv + src)) * Fd) + f4;
    float4* d = (float4*)(outF + ((size_t)(b * Kv + x)) * Fd) + f4;
    *d = *s;
}

__global__ __launch_bounds__(64) void k_fscat(const float* image, const int* accList,
                                              const u32* accCnt, const int* pos, float* outF) {
    int b = blockIdx.x >> 12, e = blockIdx.x & 4095;
    if (e >= (int)accCnt[b]) return;
    int v0 = accList[((size_t)b * TGTK + e) * 2];
    int v1 = accList[((size_t)b * TGTK + e) * 2 + 1];
    int x = pos[(size_t)b * Nv + v0];
    if (x < 0) return;
    int f = threadIdx.x;
    atomicAdd(outF + ((size_t)(b * Kv + x)) * Fd + f,
              image[((size_t)(b * Nv + v1)) * Fd + f]);
}

// ---------------- adjacency: merge rows/cols into K-bit bitsets ----------------
__global__ __launch_bounds__(256) void k_merge(const u8* adj, const u32* flags,
                                               const int* pm, u32* outbits) {
    int bi = blockIdx.x; // Bn*Nv
    int b = bi >> 13, i = bi & (Nv - 1);
    int t = pm[(size_t)b * Nv + i];
    if (t < 0) return;
    __shared__ u32 bits[Kv / 32]; // 128 words
    int tid = threadIdx.x;
    if (tid < 128) bits[tid] = 0;
    __syncthreads();
    const int* pmb = pm + (size_t)b * Nv;
    u32 fw = flags[0];
    bool bytefmt = (fw & 1) && (fw & 8);
    auto put = [&](int col) {
        int c = pmb[col];
        if (c >= 0) atomicOr(&bits[c >> 5], 1u << (c & 31));
    };
    if (bytefmt) {
        const uint4* row = (const uint4*)(adj + ((size_t)b * Nv + i) * Nv);
#pragma unroll
        for (int it = 0; it < 2; ++it) {
            uint4 v = row[it * 256 + tid];
            if (v.x | v.y | v.z | v.w) {
                int cb = (it * 256 + tid) * 16;
                u32 wv[4] = { v.x, v.y, v.z, v.w };
                for (int q = 0; q < 4; ++q) {
                    u32 u = wv[q];
                    if (!u) continue;
#pragma unroll
                    for (int kk = 0; kk < 4; ++kk)
                        if ((u >> (8 * kk)) & 0xFFu) put(cb + q * 4 + kk);
                }
            }
        }
    } else {
        const uint4* row = (const uint4*)((const u32*)adj + ((size_t)b * Nv + i) * Nv);
        for (int it = 0; it < 8; ++it) {
            uint4 v = row[it * 256 + tid];
            int cb = (it * 256 + tid) * 4;
            if (v.x) put(cb);
            if (v.y) put(cb + 1);
            if (v.z) put(cb + 2);
            if (v.w) put(cb + 3);
        }
    }
    __syncthreads();
    if (tid < 128) {
        u32 bw = bits[tid];
        if (bw) atomicOr(&outbits[((size_t)b * Kv + t) * 128 + tid], bw);
    }
}

// ---------------- expand bitsets to float adjacency, zero diagonal ----------------
__global__ void k_expand(const u32* outbits, float* out) {
    int idx = blockIdx.x; // Bn*Kv*4
    int tid = threadIdx.x;
    int b = idx >> 14, r = idx & 16383;
    int x = r >> 2, seg = r & 3;
    int c0 = seg * 1024 + tid * 4;
    u32 w = outbits[((size_t)b * Kv + x) * 128 + (c0 >> 5)];
    u32 nib = (w >> (c0 & 31)) & 0xFu;
    float4 f;
    f.x = (nib & 1) ? 1.f : 0.f;
    f.y = (nib & 2) ? 1.f : 0.f;
    f.z = (nib & 4) ? 1.f : 0.f;
    f.w = (nib & 8) ? 1.f : 0.f;
    if (x >= c0 && x < c0 + 4) ((float*)&f)[x - c0] = 0.f;
    *((float4*)(out + ((size_t)(b * Kv + x)) * Kv + c0)) = f;
}

extern "C" void kernel_launch(void* const* d_in, const int* in_sizes, int n_in,
                              void* d_out, int out_size, void* d_ws, size_t ws_size,
                              hipStream_t stream) {
    const u8* adj = (const u8*)d_in[0];
    const float* image = (const float*)d_in[1];
    const float* vs = (const float*)d_in[2];
    const int* edges = (const int*)d_in[3];
    char* ws = (char*)d_ws;
    u32* flags = (u32*)(ws + WS_FLAGS);
    u32* accCnt = (u32*)(ws + WS_ACCCNT);
    u32* outbits = (u32*)(ws + WS_OUTBITS);
    u64* keys = (u64*)(ws + WS_KEYS);
    float* sq = (float*)(ws + WS_SQ);
    u8* bnd = (u8*)(ws + WS_BND);
    int* map = (int*)(ws + WS_MAP);
    int* pos = (int*)(ws + WS_POS);
    int* pm = (int*)(ws + WS_PM);
    u32* aliveW = (u32*)(ws + WS_ALIVEW);
    int* alist = (int*)(ws + WS_ALIST);
    int* accList = (int*)(ws + WS_ACC);
    u32* pack = (u32*)(ws + WS_PACK);
    u32* spack = (u32*)(ws + WS_SPACK);
    float* outA = (float*)d_out;
    float* outF = outA + (size_t)Bn * Kv * Kv;

    hipMemsetAsync(d_ws, 0, WS_ZERO_BYTES, stream);
    k_detect<<<64, 256, 0, stream>>>(adj, flags);
    k_vertex<<<Bn * Nv / 256, 256, 0, stream>>>(image, vs, sq, bnd, map);
    k_edge<<<Bn * Ed / 256, 256, 0, stream>>>(edges, sq, bnd, keys, pack);
    // bitonic sort: local chunks, then merge stages
    k_sortA<<<Bn * 8, 1024, 0, stream>>>(keys);
    k_sortB<<<Bn * Ed / 2 / 256, 256, 0, stream>>>(keys, 16384, 8192);
    k_sortC<<<Bn * 8, 1024, 0, stream>>>(keys, 16384);
    k_sortB<<<Bn * Ed / 2 / 256, 256, 0, stream>>>(keys, 32768, 16384);
    k_sortB<<<Bn * Ed / 2 / 256, 256, 0, stream>>>(keys, 32768, 8192);
    k_sortC<<<Bn * 8, 1024, 0, stream>>>(keys, 32768);
    k_sortB<<<Bn * Ed / 2 / 256, 256, 0, stream>>>(keys, 65536, 32768);
    k_sortB<<<Bn * Ed / 2 / 256, 256, 0, stream>>>(keys, 65536, 16384);
    k_sortB<<<Bn * Ed / 2 / 256, 256, 0, stream>>>(keys, 65536, 8192);
    k_sortC<<<Bn * 8, 1024, 0, stream>>>(keys, 65536);
    k_gather<<<Bn * Ed / 256, 256, 0, stream>>>(keys, pack, spack);
    k_greedy<<<Bn, 64, 0, stream>>>(spack, map, aliveW, accList, accCnt);
    k_scan<<<Bn, 256, 0, stream>>>(aliveW, map, pos, pm, alist);
    k_fcopy<<<Bn * Kv * 16 / 256, 256, 0, stream>>>(image, alist, outF);
    k_fscat<<<Bn * TGTK, 64, 0, stream>>>(image, accList, accCnt, pos, outF);
    k_merge<<<Bn * Nv, 256, 0, stream>>>(adj, flags, pm, outbits);
    k_expand<<<Bn * Kv * 4, 256, 0, stream>>>(outbits, outA);
}